// Round 10
// baseline (938.889 us; speedup 1.0000x reference)
//
#include <hip/hip_runtime.h>
#include <hip/hip_bf16.h>
#include <math.h>

typedef unsigned short u16;
typedef __attribute__((ext_vector_type(4))) float f32x4;
typedef __attribute__((ext_vector_type(8))) __bf16 bf16x8;

#define B_    4
#define NQ_   3136
#define C_    512
#define HIMG  56
#define WIMG  56
#define HD_   4096
#define NK_   784
#define NKP_  832

static __device__ __forceinline__ float b2f(u16 u){
  union { unsigned int i; float f; } v; v.i = ((unsigned int)u)<<16; return v.f;
}
static __device__ __forceinline__ u16 f2b(float f){
  union { float f; unsigned int i; } v; v.f = f;
  unsigned int r = v.i + 0x7fffu + ((v.i>>16)&1u);
  return (u16)(r>>16);
}

#define GLD16(gsrc, ldst) __builtin_amdgcn_global_load_lds( \
    (const __attribute__((address_space(1))) void*)(gsrc), \
    (__attribute__((address_space(3))) void*)(ldst), 16, 0, 0)

// ---------------------------------------------------------------------------
// XCD-aware ordering, bx-INNER: each XCD (l&7, dispatch round-robin) owns a
// contiguous by/z panel and streams bx. Per-XCD L2 keeps its small B-panel
// resident; the big A operand is streamed once and L3 serves other XCDs'
// re-reads (HBM fetch ~= unique bytes). Identity when n%8 != 0.
// ---------------------------------------------------------------------------
static __device__ __forceinline__ void xcd_order(int &bx, int &by, int &bz){
  const int nx = gridDim.x, ny = gridDim.y, nz = gridDim.z;
  long l = blockIdx.x + (long)nx*(blockIdx.y + (long)ny*blockIdx.z);
  const long n = (long)nx*ny*nz;
  long g = ((n&7)==0) ? ((l&7)*(n>>3) + (l>>3)) : l;
  bx = (int)(g % nx); g /= nx;
  by = (int)(g % ny);
  bz = (int)(g / ny);
}

// ---------------------------------------------------------------------------
// 256x128 4-wave bf16 GEMM v6: wave tile 128x64 (384 B ds_read per MFMA,
// 2x MFMA per tile-period vs v5's 64x64 -> halves relative fixed overhead).
// C[m,n] = (sum_k A[m,k]*B[n,k] + bias1[n]) * hscale * scalePtr[z] (+bias2).
// A:(M,K) stride sA; B:(N,K) stride sB. BK=32. Waves 2(M)x2(N).
// LDS 72 KiB: A 3 x 16K @0, B 3 x 8K @48K -> 2 blocks/CU (launch_bounds(256,2),
// acc[8][4] ~205 VGPR -> 2 waves/SIMD).
// Tile j (buf=j%3):
//   vmcnt(6|0 last); s_barrier     -> tile j in LDS; buf (j+2)%3 free
//   12x ds_read_b128 (af[8],bf[4]); STAGE(j+2 -> (j+2)%3) 6 GLD16/thread;
//   setprio(1) 32 MFMA setprio(0)
// Ring-safety: buf (j+2)%3 held tile j-1; every wave's tile j-1 ds_reads
// completed before its MFMAs (lgkmcnt), so post-barrier staging is race-free.
// Swizzle: LDS[row][c8] = src[row][c8 ^ ((row>>1)&3)] via pre-swizzled global
// column; reads XOR the same term (measured conflict-free, r5-r9).
// Loads NOT masked (caller guarantees over-read slack); stores masked.
// Requires K%32==0, K>=64.
// ---------------------------------------------------------------------------
template<int OUT_F32>
__global__ __launch_bounds__(256, 2)
void gemm128(const u16* __restrict__ A, const u16* __restrict__ Bm, void* __restrict__ Cm,
             int M, int Ncols, int K, int sA, int sB, int sC, int zdiv,
             long long zA1, long long zA2, long long zB1, long long zB2,
             long long zC1, long long zC2,
             const float* __restrict__ bias1, float hscale,
             const float* __restrict__ scalePtr,
             const float* __restrict__ bias2, int rowsPerB, int b2s)
{
  __shared__ u16 lds[36864];     // 72 KiB: A 3x8192 u16 @0, B 3x4096 u16 @24576
  int bx, by, z;
  xcd_order(bx, by, z);
  const int zq = z / zdiv, zr = z % zdiv;
  const u16* Ab = A  + (long long)zq*zA1 + (long long)zr*zA2;
  const u16* Bb = Bm + (long long)zq*zB1 + (long long)zr*zB2;
  const int m0 = bx*256, n0 = by*128;
  const int t = threadIdx.x, w = t>>6, lane = t&63;
  const int wm = w>>1, wn = w&1;             // 2 x 2 wave grid
  const int l15 = lane & 15;

  // staging: 4 threads/row (32 elems), 64 rows/instr; pre-swizzled source col
  const int srow = t>>2;                                   // 0..63
  const int scol = (((t&3) ^ ((srow>>1)&3)) << 3);         // elems (8-chunks)
  const u16* aS = Ab + (long long)(m0 + srow)*sA + scol;
  const u16* bS = Bb + (long long)(n0 + srow)*sB + scol;
  const long long sA64 = (long long)64*sA, sB64 = (long long)64*sB;
  const int w512 = w*512;                                  // wave base (u16)

#define STAGE(jt, buf) do{                                        \
    const u16* a0_ = aS + (long long)(jt)*32;                     \
    const u16* b0_ = bS + (long long)(jt)*32;                     \
    u16* la_ = lds + (buf)*8192 + w512;                           \
    u16* lb_ = lds + 24576 + (buf)*4096 + w512;                   \
    GLD16(a0_,          la_);                                     \
    GLD16(a0_ +   sA64, la_ + 2048);                              \
    GLD16(a0_ + 2*sA64, la_ + 4096);                              \
    GLD16(a0_ + 3*sA64, la_ + 6144);                              \
    GLD16(b0_,          lb_);                                     \
    GLD16(b0_ +   sB64, lb_ + 2048);                              \
  }while(0)

  f32x4 acc[8][4];
#pragma unroll
  for(int i=0;i<8;i++)
#pragma unroll
    for(int j=0;j<4;j++) acc[i][j] = (f32x4)(0.0f);

  const char* ldsc = (const char*)lds;
  const int ck = (((lane>>4) ^ ((lane>>1)&3)) << 4);   // swizzled chunk (bytes)
  const int aRowB = (wm*128 + l15) * 64;               // A row byte base
  const int bRowB = (wn*64  + l15) * 64;               // B row byte base

  const int T = K >> 5;
  STAGE(0, 0);
  STAGE(1, 1);

  int buf = 0;
  for(int j=0; j<T; j++){
    if(j == T-1) asm volatile("s_waitcnt vmcnt(0)" ::: "memory");
    else         asm volatile("s_waitcnt vmcnt(6)" ::: "memory");
    asm volatile("s_barrier" ::: "memory");   // tile j visible; buf (j+2)%3 free

    const int aBuf = buf*16384 + aRowB;
    const int bBuf = 49152 + buf*8192 + bRowB;
    bf16x8 af[8], bfv[4];
#pragma unroll
    for(int fr=0; fr<8; fr++) af[fr]  = *(const bf16x8*)(ldsc + aBuf + fr*1024 + ck);
#pragma unroll
    for(int fn=0; fn<4; fn++) bfv[fn] = *(const bf16x8*)(ldsc + bBuf + fn*1024 + ck);
    {
      const int nbuf = (buf+2 >= 3) ? buf-1 : buf+2;
      if(j+2 < T) STAGE(j+2, nbuf);
    }
    __builtin_amdgcn_s_setprio(1);
#pragma unroll
    for(int fr=0; fr<8; fr++)
#pragma unroll
      for(int fn=0; fn<4; fn++)
        acc[fr][fn] = __builtin_amdgcn_mfma_f32_16x16x32_bf16(af[fr], bfv[fn], acc[fr][fn], 0,0,0);
    __builtin_amdgcn_s_setprio(0);
    buf = (buf+1 >= 3) ? 0 : buf+1;
  }
#undef STAGE

  const float dsc = scalePtr ? scalePtr[z] : 1.0f;
  const long long cBase = (long long)zq*zC1 + (long long)zr*zC2;
  const int r4 = (lane>>4)*4;
#pragma unroll
  for(int mf=0; mf<8; mf++){
    const int row0 = m0 + wm*128 + mf*16 + r4;
#pragma unroll
    for(int nf=0; nf<4; nf++){
      const int col = n0 + wn*64 + nf*16 + l15;
      if(col < Ncols){
#pragma unroll
        for(int r=0;r<4;r++){
          const int row = row0 + r;
          if(row < M){
            float v = acc[mf][nf][r];
            if(bias1) v += bias1[col];
            v *= hscale * dsc;
            if(bias2) v += bias2[(row/rowsPerB)*b2s + col];
            if(OUT_F32) ((float*)Cm)[cBase + (long long)row*sC + col] = v;
            else        ((u16*) Cm)[cBase + (long long)row*sC + col] = f2b(v);
          }
        }
      }
    }
  }
}

// f32 (K,N) weight -> bf16 (N,K) transpose
__global__ __launch_bounds__(256)
void wt_kernel(const float* __restrict__ W, u16* __restrict__ Wt, int K, int N){
  __shared__ float tile[32][33];
  const int n0 = blockIdx.x*32, k0 = blockIdx.y*32;
  const int t = threadIdx.x, tr = t>>5, tc = t&31;
#pragma unroll
  for(int i=0;i<4;i++)
    tile[tr+i*8][tc] = W[(long long)(k0+tr+i*8)*N + n0+tc];
  __syncthreads();
#pragma unroll
  for(int i=0;i<4;i++)
    Wt[(long long)(n0+tr+i*8)*K + k0+tc] = f2b(tile[tc][tr+i*8]);
}

__global__ __launch_bounds__(256)
void cvt_bf16(const float* __restrict__ in, u16* __restrict__ outp, long long n){
  long long i = ((long long)blockIdx.x*256 + threadIdx.x)*4;
  if(i+3 < n){
    float4 v = *(const float4*)(in+i);
    ushort4 o; o.x=f2b(v.x); o.y=f2b(v.y); o.z=f2b(v.z); o.w=f2b(v.w);
    *(ushort4*)(outp+i) = o;
  }
}

// depthwise 3x3 stride-2 SAME conv (pad lo=0,hi=1) + bias + LayerNorm -> bf16
__global__ __launch_bounds__(256)
void conv_ln(const float* __restrict__ q, const float* __restrict__ ker,
             const float* __restrict__ cbias, const float* __restrict__ gamma,
             const float* __restrict__ beta, u16* __restrict__ xo)
{
  const int p = blockIdx.x;
  const int b = p / 784, pix = p % 784;
  const int oy = pix / 28, ox = pix % 28;
  const int t = threadIdx.x;
  __shared__ float red[256];
  float v[2];
#pragma unroll
  for(int e=0;e<2;e++){
    const int c = t + e*256;
    float acc = cbias[c];
    for(int ky=0;ky<3;ky++){
      const int y = oy*2 + ky;
      if(y >= HIMG) continue;
      for(int kx=0;kx<3;kx++){
        const int x = ox*2 + kx;
        if(x >= WIMG) continue;
        acc += q[(((long long)b*HIMG + y)*WIMG + x)*C_ + c] * ker[(ky*3+kx)*C_ + c];
      }
    }
    v[e] = acc;
  }
  red[t]=v[0]+v[1]; __syncthreads();
  for(int st=128; st>0; st>>=1){ if(t<st) red[t]+=red[t+st]; __syncthreads(); }
  const float mu = red[0] * (1.0f/C_);
  __syncthreads();
  const float d0=v[0]-mu, d1=v[1]-mu;
  red[t]=d0*d0+d1*d1; __syncthreads();
  for(int st=128; st>0; st>>=1){ if(t<st) red[t]+=red[t+st]; __syncthreads(); }
  const float rs = rsqrtf(red[0]*(1.0f/C_) + 1e-3f);
  const long long ob = (long long)p*C_;
#pragma unroll
  for(int e=0;e<2;e++){
    const int c = t+e*256;
    xo[ob+c] = f2b((v[e]-mu)*rs*gamma[c] + beta[c]);
  }
}

// per-batch: V part of KV_b (784 x 4096, row stride sV) -> Vt_b (4096,832), k zero-padded
__global__ __launch_bounds__(256)
void vt_kernel(const u16* __restrict__ Vf_b, u16* __restrict__ Vt_b, int sV){
  __shared__ u16 tile[32][33];
  const int k0 = blockIdx.x*32, d0 = blockIdx.y*32;
  const int t = threadIdx.x, tr = t>>5, tc = t&31;
#pragma unroll
  for(int i=0;i<4;i++){
    const int k = k0+tr+i*8;
    tile[tr+i*8][tc] = (k < NK_) ? Vf_b[(long long)k*sV + d0+tc] : (u16)0;
  }
  __syncthreads();
#pragma unroll
  for(int i=0;i<4;i++)
    Vt_b[(long long)(d0+tr+i*8)*NKP_ + k0+tc] = tile[tc][tr+i*8];
}

// ---------------------------------------------------------------------------
// Wave-parallel mix+softmax: one block (512 thr = 8 waves) per q-row.
// Unique-slot partial sums (no hot atomics). Zeroes pad cols 784..831.
// ---------------------------------------------------------------------------
__global__ __launch_bounds__(512)
void mix_softmax(u16* __restrict__ S_b, const float* __restrict__ tw,
                 float* __restrict__ partial_b)
{
  const int qi = blockIdx.x;
  const int t = threadIdx.x;
  const int wave = t >> 6, lane = t & 63;
  __shared__ float sv[8*NK_];
  const long long rowstr = (long long)NQ_*NKP_;
  const long long base = (long long)qi*NKP_;

  for(int idx = t; idx < 8*196; idx += 512){
    const int h = idx / 196, c4 = idx % 196;
    ushort4 u4 = *(const ushort4*)(S_b + base + h*rowstr + c4*4);
    float* d = sv + h*NK_ + c4*4;
    d[0]=b2f(u4.x); d[1]=b2f(u4.y); d[2]=b2f(u4.z); d[3]=b2f(u4.w);
  }
  __syncthreads();

  const int g = wave;
  float wgt[8];
#pragma unroll
  for(int h=0;h<8;h++) wgt[h] = tw[h*8+g];

  float xs[13];
  float lmax = -1e30f;
#pragma unroll
  for(int j=0;j<13;j++){
    const int k = j*64 + lane;
    if(k < NK_){
      float x = 0.f;
#pragma unroll
      for(int h=0;h<8;h++) x += wgt[h]*sv[h*NK_+k];
      xs[j] = x;
      lmax = fmaxf(lmax, x);
    } else xs[j] = -1e30f;
  }
#pragma unroll
  for(int off=32; off>=1; off>>=1) lmax = fmaxf(lmax, __shfl_xor(lmax, off));

  float lsum = 0.f;
#pragma unroll
  for(int j=0;j<13;j++){
    const int k = j*64 + lane;
    if(k < NK_){
      const float e = __expf(xs[j] - lmax);
      xs[j] = e; lsum += e;
    }
  }
#pragma unroll
  for(int off=32; off>=1; off>>=1) lsum += __shfl_xor(lsum, off);
  const float inv = 1.0f/lsum;

  u16* dst = S_b + base + g*rowstr;
  float lss = 0.f;
#pragma unroll
  for(int j=0;j<13;j++){
    const int k = j*64 + lane;
    if(k < NK_){
      const float dev = xs[j]*inv - (1.0f/NK_);
      dst[k] = f2b(dev);
      lss += dev*dev;
    }
  }
  for(int k = NK_ + lane; k < NKP_; k += 64) dst[k] = 0;
#pragma unroll
  for(int off=32; off>=1; off>>=1) lss += __shfl_xor(lss, off);
  if(lane==0) partial_b[g*NQ_ + qi] = lss;
}

// column sums of V, k-split into 8 chunks of 98 -> part[kc][hd]
__global__ __launch_bounds__(256)
void colsum_v(const u16* __restrict__ Vf_b, float* __restrict__ part, int sV){
  const int hd = blockIdx.x*256 + threadIdx.x;
  const int kc = blockIdx.y;
  const u16* p = Vf_b + (long long)kc*98*sV + hd;
  float s=0.f;
  for(int k=0;k<98;k++) s += b2f(p[(long long)k*sV]);
  part[(long long)kc*HD_ + hd] = s;
}

__global__ __launch_bounds__(256)
void finalize_stats(const float* __restrict__ partial_b, const float* __restrict__ bng_b,
                    const float* __restrict__ bnb_b, float* __restrict__ a_b,
                    float* __restrict__ c_b){
  const int g = blockIdx.x;
  const int t = threadIdx.x;
  __shared__ float red[4];
  float s = 0.f;
  for(int i=t; i<NQ_; i+=256) s += partial_b[g*NQ_ + i];
#pragma unroll
  for(int off=32; off>=1; off>>=1) s += __shfl_xor(s, off);
  if((t&63)==0) red[t>>6] = s;
  __syncthreads();
  if(t==0){
    const float tot = red[0]+red[1]+red[2]+red[3];
    const float s2 = tot * (1.0f/((float)NQ_*(float)NK_));
    a_b[g] = bng_b[g]*rsqrtf(s2 + 1e-3f);
    c_b[g] = bnb_b[g];
  }
}

// corr_b[n] = sum_g c_b[g] * (colsumV_b[g*512:(g+1)*512] . Wo_g[:,n]); colsum k-split
__global__ __launch_bounds__(256)
void corr_kernel(const float* __restrict__ part, const u16* __restrict__ Wot,
                 const float* __restrict__ c_b, float* __restrict__ corr_b){
  const int n = blockIdx.x, t = threadIdx.x;
  __shared__ float red[256];
  float s = 0.f;
  for(int hd=t; hd<HD_; hd+=256){
    float cs = 0.f;
#pragma unroll
    for(int kc=0; kc<8; kc++) cs += part[(long long)kc*HD_ + hd];
    s += c_b[hd>>9] * cs * b2f(Wot[(long long)n*HD_+hd]);
  }
  red[t]=s; __syncthreads();
  for(int st=128; st>0; st>>=1){ if(t<st) red[t]+=red[t+st]; __syncthreads(); }
  if(t==0) corr_b[n]=red[0];
}

// ---------------------------------------------------------------------------
extern "C" void kernel_launch(void* const* d_in, const int* in_sizes, int n_in,
                              void* d_out, int out_size, void* d_ws, size_t ws_size,
                              hipStream_t stream)
{
  (void)in_sizes; (void)n_in; (void)out_size;
  const float* queries = (const float*)d_in[0];
  const float* Wq  = (const float*)d_in[3];
  const float* bq  = (const float*)d_in[4];
  const float* Wk  = (const float*)d_in[5];
  const float* bk  = (const float*)d_in[6];
  const float* Wv  = (const float*)d_in[7];
  const float* bv  = (const float*)d_in[8];
  const float* Wo  = (const float*)d_in[9];
  const float* bo  = (const float*)d_in[10];
  const float* srk = (const float*)d_in[11];
  const float* srb = (const float*)d_in[12];
  const float* lng = (const float*)d_in[13];
  const float* lnb = (const float*)d_in[14];
  const float* tw  = (const float*)d_in[15];
  const float* bng = (const float*)d_in[17];
  const float* bnb = (const float*)d_in[18];
  float* out = (float*)d_out;
  const float QSC = 0.04419417382415922f;   // 1/sqrt(512)

  char* w = (char*)d_ws;
  size_t off = 0;
  auto alloc = [&](size_t bytes)->char*{
    char* p = w + off; off += (bytes + 255) & ~(size_t)255; return p;
  };

  const bool tierA = (ws_size >= (size_t)210*1024*1024);

  u16* Wqt = (u16*)alloc((size_t)HD_*C_*2);
  u16* Wkt = (u16*)alloc((size_t)HD_*C_*2);   // Wvt follows contiguously
  u16* Wvt = (u16*)alloc((size_t)HD_*C_*2);
  u16* Wot = (u16*)alloc((size_t)C_*HD_*2);
  u16* x   = (u16*)alloc((size_t)B_*NK_*C_*2 + 262144);     // +256K over-read pad
  float* bkv = (float*)alloc((size_t)2*HD_*4);              // bk || bv
  u16* Qin;
  u16* QfU;
  if(tierA){
    Qin = (u16*)alloc((size_t)B_*NQ_*C_*2);
    QfU = (u16*)alloc((size_t)B_*NQ_*HD_*2 + 2097152);      // +2M: score A over-read (191 rows)
  } else {
    Qin = (u16*)alloc((size_t)NQ_*C_*2 + 262144);
    QfU = (u16*)alloc((size_t)NQ_*HD_*2 + 2097152);
  }
  u16* KV_b = (u16*)alloc((size_t)NK_*2*HD_*2 + 4194304);  // +4M: score B over-read
  u16* Vt_b = (u16*)alloc((size_t)HD_*NKP_*2);
  u16* S_b  = (u16*)alloc((size_t)8*NQ_*NKP_*2 + 524288);   // +512K PV A over-read pad
  float* colsum  = (float*)alloc((size_t)8*HD_*4);          // k-split partials (per batch)
  float* partial = (float*)alloc((size_t)8*NQ_*4);
  float* aArr    = (float*)alloc(256);
  float* cArr    = (float*)alloc(256);
  float* corrB   = (float*)alloc((size_t)B_*C_*4);

  // ---- weight prep + conv+LN ----
  wt_kernel<<<dim3(128,16), 256, 0, stream>>>(Wq, Wqt, 512, 4096);
  wt_kernel<<<dim3(128,16), 256, 0, stream>>>(Wk, Wkt, 512, 4096);
  wt_kernel<<<dim3(128,16), 256, 0, stream>>>(Wv, Wvt, 512, 4096);
  wt_kernel<<<dim3(16,128), 256, 0, stream>>>(Wo, Wot, 4096, 512);
  conv_ln<<<B_*NK_, 256, 0, stream>>>(queries, srk, srb, lng, lnb, x);
  hipMemcpyAsync(bkv,      bk, HD_*4, hipMemcpyDeviceToDevice, stream);
  hipMemcpyAsync(bkv+HD_,  bv, HD_*4, hipMemcpyDeviceToDevice, stream);

  if(tierA){
    cvt_bf16<<<6272, 256, 0, stream>>>(queries, Qin, (long long)B_*NQ_*C_);
    // Qf = (queries@Wq + bq)/sqrt(512)
    gemm128<0><<<dim3(49,32,1),256,0,stream>>>(Qin, Wqt, QfU, B_*NQ_, 4096, 512,
        512, 512, HD_, 1, 0,0,0,0,0,0, bq, QSC, nullptr, nullptr, 1, 0);
  }

  for(int b=0; b<B_; b++){
    u16* Qf_b = tierA ? (QfU + (size_t)b*NQ_*HD_) : QfU;
    if(!tierA){
      cvt_bf16<<<1568, 256, 0, stream>>>(queries + (size_t)b*NQ_*C_, Qin, (long long)NQ_*C_);
      gemm128<0><<<dim3(13,32,1),256,0,stream>>>(Qin, Wqt, Qf_b, NQ_, 4096, 512,
          512, 512, HD_, 1, 0,0,0,0,0,0, bq, QSC, nullptr, nullptr, 1, 0);
    }
    const u16* x_b = x + (size_t)b*NK_*C_;
    // combined K|V projection: B spans Wkt..Wvt (adjacent, 8192 rows)
    gemm128<0><<<dim3(4,64,1),256,0,stream>>>(x_b, Wkt, KV_b, NK_, 2*HD_, 512,
        512, 512, 2*HD_, 1, 0,0,0,0,0,0, bkv, 1.0f, nullptr, nullptr, 1, 0);
    vt_kernel<<<dim3(26,128),256,0,stream>>>(KV_b + HD_, Vt_b, 2*HD_);
    colsum_v<<<dim3(16,8),256,0,stream>>>(KV_b + HD_, colsum, 2*HD_);
    // per-head scores: S_b[z] = Qf_b[:, z*512:+512] @ K_b[:, z*512:+512]^T
    gemm128<0><<<dim3(13,7,8),256,0,stream>>>(Qf_b, KV_b, S_b, NQ_, NKP_, 512,
        HD_, 2*HD_, NKP_, 8, 0, 512, 0, 512, 0, (long long)NQ_*NKP_,
        nullptr, 1.0f, nullptr, nullptr, 1, 0);
    mix_softmax<<<NQ_, 512, 0, stream>>>(S_b, tw, partial);
    finalize_stats<<<8,256,0,stream>>>(partial, bng + b*8, bnb + b*8, aArr + b*8, cArr + b*8);
    corr_kernel<<<512,256,0,stream>>>(colsum, Wot, cArr + b*8, corrB + b*C_);
    // U_b[:, z*512+d] = a[b,z] * (P~_z @ V_z)
    gemm128<0><<<dim3(13,4,8),256,0,stream>>>(S_b, Vt_b, Qf_b, NQ_, 512, NKP_,
        NKP_, NKP_, HD_, 8, 0, (long long)NQ_*NKP_, 0, (long long)512*NKP_, 0, 512,
        nullptr, 1.0f, aArr + b*8, nullptr, 1, 0);
    if(!tierA){
      gemm128<1><<<dim3(13,4,1),256,0,stream>>>(Qf_b, Wot, out + (size_t)b*NQ_*C_,
          NQ_, 512, HD_, HD_, HD_, C_,
          1, 0,0,0,0,0,0, bo, 1.0f, nullptr, corrB + b*C_, NQ_, C_);
    }
  }

  if(tierA){
    gemm128<1><<<dim3(49,4,1),256,0,stream>>>(QfU, Wot, out, B_*NQ_, 512, HD_,
        HD_, HD_, C_, 1, 0,0,0,0,0,0, bo, 1.0f, nullptr, corrB, NQ_, C_);
  }
}

// Round 11
// 926.977 us; speedup vs baseline: 1.0129x; 1.0129x over previous
//
#include <hip/hip_runtime.h>
#include <hip/hip_bf16.h>
#include <math.h>

typedef unsigned short u16;
typedef __attribute__((ext_vector_type(4))) float f32x4;
typedef __attribute__((ext_vector_type(8))) __bf16 bf16x8;

#define B_    4
#define NQ_   3136
#define C_    512
#define HIMG  56
#define WIMG  56
#define HD_   4096
#define NK_   784
#define NKP_  832

static __device__ __forceinline__ float b2f(u16 u){
  union { unsigned int i; float f; } v; v.i = ((unsigned int)u)<<16; return v.f;
}
static __device__ __forceinline__ u16 f2b(float f){
  union { float f; unsigned int i; } v; v.f = f;
  unsigned int r = v.i + 0x7fffu + ((v.i>>16)&1u);
  return (u16)(r>>16);
}

#define GLD16(gsrc, ldst) __builtin_amdgcn_global_load_lds( \
    (const __attribute__((address_space(1))) void*)(gsrc), \
    (__attribute__((address_space(3))) void*)(ldst), 16, 0, 0)

// ---------------------------------------------------------------------------
// Block-order decodes. HW dispatches blocks round-robin to XCDs by linear id
// (xcd = l%8); the remap makes each XCD's block SEQUENCE walk logically
// adjacent tiles so its private 4MB L2 gets operand-panel reuse.
//
// (a) m204-bijective, by-INNER, z-outer: consecutive ranks on one XCD share
//     bx (A-tile L2-resident across the ny sweep) and one z slice.
// (b) panel decode (z==1): mp x np grid of (M,N) panels, one per XCD; within
//     a panel by-inner. B-panel stays L2-resident; A-panel streamed once.
// ---------------------------------------------------------------------------
static __device__ __forceinline__ long xcd_rank(long n){
  const long l = blockIdx.x + (long)gridDim.x*(blockIdx.y + (long)gridDim.y*blockIdx.z);
  const long q8 = n>>3, r8 = n&7;
  const long xcd = l&7, idx = l>>3;
  return (xcd<r8 ? xcd*(q8+1) : r8*(q8+1) + (xcd-r8)*q8) + idx;
}
static __device__ __forceinline__ void order_byinner(int &bx, int &by, int &bz){
  const int nx = gridDim.x, ny = gridDim.y, nz = gridDim.z;
  long g = xcd_rank((long)nx*ny*nz);
  by = (int)(g % ny); g /= ny;
  bx = (int)(g % nx);
  bz = (int)(g / nx);
}
static __device__ __forceinline__ void order_panel(int mp, int np, int &bx, int &by){
  const int nx = gridDim.x, ny = gridDim.y;
  int rem = (int)xcd_rank((long)nx*ny);
  int mi = 0, ni = 0;
  for(int p = 0; p < mp*np; p++){
    mi = p/np; ni = p%np;
    const int sx = nx/mp + (mi < nx%mp ? 1 : 0);
    const int sy = ny/np + (ni < ny%np ? 1 : 0);
    const int cnt = sx*sy;
    if(rem < cnt) break;
    rem -= cnt;
  }
  const int sy = ny/np + (ni < ny%np ? 1 : 0);
  const int basex = mi*(nx/mp) + (mi < nx%mp ? mi : nx%mp);
  const int basey = ni*(ny/np) + (ni < ny%np ? ni : ny%np);
  bx = basex + rem / sy;
  by = basey + rem % sy;
}

// ---------------------------------------------------------------------------
// 256x128 4-wave bf16 GEMM v7 = v6 core + L2-panel block ordering.
// C[m,n] = (sum_k A[m,k]*B[n,k] + bias1[n]) * hscale * scalePtr[z] (+bias2).
// A:(M,K) stride sA; B:(N,K) stride sB. BK=32. Waves 2(M)x2(N), wave 128x64.
// LDS 72 KiB (A 3x16K, B 3x8K) -> 2 blocks/CU. Tile j (buf=j%3):
//   vmcnt(6|0 last); s_barrier; 12x ds_read_b128; STAGE(j+2); setprio(1)
//   32 MFMA setprio(0).
// Swizzle: LDS[row][c8] = src[row][c8 ^ ((row>>1)&3)] (pre-swizzled global
// col + XOR on read; measured conflict-free r5-r10).
// mp>0: panel order (z must be 1). mp==0: by-inner m204 order.
// Loads NOT masked (caller guarantees over-read slack); stores masked.
// Requires K%32==0, K>=64.
// ---------------------------------------------------------------------------
template<int OUT_F32>
__global__ __launch_bounds__(256, 2)
void gemm128(const u16* __restrict__ A, const u16* __restrict__ Bm, void* __restrict__ Cm,
             int M, int Ncols, int K, int sA, int sB, int sC, int zdiv,
             long long zA1, long long zA2, long long zB1, long long zB2,
             long long zC1, long long zC2,
             const float* __restrict__ bias1, float hscale,
             const float* __restrict__ scalePtr,
             const float* __restrict__ bias2, int rowsPerB, int b2s,
             int mp, int np)
{
  __shared__ u16 lds[36864];     // 72 KiB
  int bx, by, z;
  if(mp > 0){ order_panel(mp, np, bx, by); z = 0; }
  else      { order_byinner(bx, by, z); }
  const int zq = z / zdiv, zr = z % zdiv;
  const u16* Ab = A  + (long long)zq*zA1 + (long long)zr*zA2;
  const u16* Bb = Bm + (long long)zq*zB1 + (long long)zr*zB2;
  const int m0 = bx*256, n0 = by*128;
  const int t = threadIdx.x, w = t>>6, lane = t&63;
  const int wm = w>>1, wn = w&1;             // 2 x 2 wave grid
  const int l15 = lane & 15;

  // staging: 4 threads/row (32 elems), 64 rows/instr; pre-swizzled source col
  const int srow = t>>2;                                   // 0..63
  const int scol = (((t&3) ^ ((srow>>1)&3)) << 3);         // elems (8-chunks)
  const u16* aS = Ab + (long long)(m0 + srow)*sA + scol;
  const u16* bS = Bb + (long long)(n0 + srow)*sB + scol;
  const long long sA64 = (long long)64*sA, sB64 = (long long)64*sB;
  const int w512 = w*512;                                  // wave base (u16)

#define STAGE(jt, buf) do{                                        \
    const u16* a0_ = aS + (long long)(jt)*32;                     \
    const u16* b0_ = bS + (long long)(jt)*32;                     \
    u16* la_ = lds + (buf)*8192 + w512;                           \
    u16* lb_ = lds + 24576 + (buf)*4096 + w512;                   \
    GLD16(a0_,          la_);                                     \
    GLD16(a0_ +   sA64, la_ + 2048);                              \
    GLD16(a0_ + 2*sA64, la_ + 4096);                              \
    GLD16(a0_ + 3*sA64, la_ + 6144);                              \
    GLD16(b0_,          lb_);                                     \
    GLD16(b0_ +   sB64, lb_ + 2048);                              \
  }while(0)

  f32x4 acc[8][4];
#pragma unroll
  for(int i=0;i<8;i++)
#pragma unroll
    for(int j=0;j<4;j++) acc[i][j] = (f32x4)(0.0f);

  const char* ldsc = (const char*)lds;
  const int ck = (((lane>>4) ^ ((lane>>1)&3)) << 4);   // swizzled chunk (bytes)
  const int aRowB = (wm*128 + l15) * 64;               // A row byte base
  const int bRowB = (wn*64  + l15) * 64;               // B row byte base

  const int T = K >> 5;
  STAGE(0, 0);
  STAGE(1, 1);

  int buf = 0;
  for(int j=0; j<T; j++){
    if(j == T-1) asm volatile("s_waitcnt vmcnt(0)" ::: "memory");
    else         asm volatile("s_waitcnt vmcnt(6)" ::: "memory");
    asm volatile("s_barrier" ::: "memory");   // tile j visible; buf (j+2)%3 free

    const int aBuf = buf*16384 + aRowB;
    const int bBuf = 49152 + buf*8192 + bRowB;
    bf16x8 af[8], bfv[4];
#pragma unroll
    for(int fr=0; fr<8; fr++) af[fr]  = *(const bf16x8*)(ldsc + aBuf + fr*1024 + ck);
#pragma unroll
    for(int fn=0; fn<4; fn++) bfv[fn] = *(const bf16x8*)(ldsc + bBuf + fn*1024 + ck);
    {
      const int nbuf = (buf+2 >= 3) ? buf-1 : buf+2;
      if(j+2 < T) STAGE(j+2, nbuf);
    }
    __builtin_amdgcn_s_setprio(1);
#pragma unroll
    for(int fr=0; fr<8; fr++)
#pragma unroll
      for(int fn=0; fn<4; fn++)
        acc[fr][fn] = __builtin_amdgcn_mfma_f32_16x16x32_bf16(af[fr], bfv[fn], acc[fr][fn], 0,0,0);
    __builtin_amdgcn_s_setprio(0);
    buf = (buf+1 >= 3) ? 0 : buf+1;
  }
#undef STAGE

  const float dsc = scalePtr ? scalePtr[z] : 1.0f;
  const long long cBase = (long long)zq*zC1 + (long long)zr*zC2;
  const int r4 = (lane>>4)*4;
#pragma unroll
  for(int mf=0; mf<8; mf++){
    const int row0 = m0 + wm*128 + mf*16 + r4;
#pragma unroll
    for(int nf=0; nf<4; nf++){
      const int col = n0 + wn*64 + nf*16 + l15;
      if(col < Ncols){
#pragma unroll
        for(int r=0;r<4;r++){
          const int row = row0 + r;
          if(row < M){
            float v = acc[mf][nf][r];
            if(bias1) v += bias1[col];
            v *= hscale * dsc;
            if(bias2) v += bias2[(row/rowsPerB)*b2s + col];
            if(OUT_F32) ((float*)Cm)[cBase + (long long)row*sC + col] = v;
            else        ((u16*) Cm)[cBase + (long long)row*sC + col] = f2b(v);
          }
        }
      }
    }
  }
}

// f32 (K,N) weight -> bf16 (N,K) transpose
__global__ __launch_bounds__(256)
void wt_kernel(const float* __restrict__ W, u16* __restrict__ Wt, int K, int N){
  __shared__ float tile[32][33];
  const int n0 = blockIdx.x*32, k0 = blockIdx.y*32;
  const int t = threadIdx.x, tr = t>>5, tc = t&31;
#pragma unroll
  for(int i=0;i<4;i++)
    tile[tr+i*8][tc] = W[(long long)(k0+tr+i*8)*N + n0+tc];
  __syncthreads();
#pragma unroll
  for(int i=0;i<4;i++)
    Wt[(long long)(n0+tr+i*8)*K + k0+tc] = f2b(tile[tc][tr+i*8]);
}

__global__ __launch_bounds__(256)
void cvt_bf16(const float* __restrict__ in, u16* __restrict__ outp, long long n){
  long long i = ((long long)blockIdx.x*256 + threadIdx.x)*4;
  if(i+3 < n){
    float4 v = *(const float4*)(in+i);
    ushort4 o; o.x=f2b(v.x); o.y=f2b(v.y); o.z=f2b(v.z); o.w=f2b(v.w);
    *(ushort4*)(outp+i) = o;
  }
}

// depthwise 3x3 stride-2 SAME conv (pad lo=0,hi=1) + bias + LayerNorm -> bf16
__global__ __launch_bounds__(256)
void conv_ln(const float* __restrict__ q, const float* __restrict__ ker,
             const float* __restrict__ cbias, const float* __restrict__ gamma,
             const float* __restrict__ beta, u16* __restrict__ xo)
{
  const int p = blockIdx.x;
  const int b = p / 784, pix = p % 784;
  const int oy = pix / 28, ox = pix % 28;
  const int t = threadIdx.x;
  __shared__ float red[256];
  float v[2];
#pragma unroll
  for(int e=0;e<2;e++){
    const int c = t + e*256;
    float acc = cbias[c];
    for(int ky=0;ky<3;ky++){
      const int y = oy*2 + ky;
      if(y >= HIMG) continue;
      for(int kx=0;kx<3;kx++){
        const int x = ox*2 + kx;
        if(x >= WIMG) continue;
        acc += q[(((long long)b*HIMG + y)*WIMG + x)*C_ + c] * ker[(ky*3+kx)*C_ + c];
      }
    }
    v[e] = acc;
  }
  red[t]=v[0]+v[1]; __syncthreads();
  for(int st=128; st>0; st>>=1){ if(t<st) red[t]+=red[t+st]; __syncthreads(); }
  const float mu = red[0] * (1.0f/C_);
  __syncthreads();
  const float d0=v[0]-mu, d1=v[1]-mu;
  red[t]=d0*d0+d1*d1; __syncthreads();
  for(int st=128; st>0; st>>=1){ if(t<st) red[t]+=red[t+st]; __syncthreads(); }
  const float rs = rsqrtf(red[0]*(1.0f/C_) + 1e-3f);
  const long long ob = (long long)p*C_;
#pragma unroll
  for(int e=0;e<2;e++){
    const int c = t+e*256;
    xo[ob+c] = f2b((v[e]-mu)*rs*gamma[c] + beta[c]);
  }
}

// per-batch: V part of KV_b (784 x 4096, row stride sV) -> Vt_b (4096,832), k zero-padded
__global__ __launch_bounds__(256)
void vt_kernel(const u16* __restrict__ Vf_b, u16* __restrict__ Vt_b, int sV){
  __shared__ u16 tile[32][33];
  const int k0 = blockIdx.x*32, d0 = blockIdx.y*32;
  const int t = threadIdx.x, tr = t>>5, tc = t&31;
#pragma unroll
  for(int i=0;i<4;i++){
    const int k = k0+tr+i*8;
    tile[tr+i*8][tc] = (k < NK_) ? Vf_b[(long long)k*sV + d0+tc] : (u16)0;
  }
  __syncthreads();
#pragma unroll
  for(int i=0;i<4;i++)
    Vt_b[(long long)(d0+tr+i*8)*NKP_ + k0+tc] = tile[tc][tr+i*8];
}

// ---------------------------------------------------------------------------
// Wave-parallel mix+softmax: one block (512 thr = 8 waves) per q-row.
// Unique-slot partial sums (no hot atomics). Zeroes pad cols 784..831.
// ---------------------------------------------------------------------------
__global__ __launch_bounds__(512)
void mix_softmax(u16* __restrict__ S_b, const float* __restrict__ tw,
                 float* __restrict__ partial_b)
{
  const int qi = blockIdx.x;
  const int t = threadIdx.x;
  const int wave = t >> 6, lane = t & 63;
  __shared__ float sv[8*NK_];
  const long long rowstr = (long long)NQ_*NKP_;
  const long long base = (long long)qi*NKP_;

  for(int idx = t; idx < 8*196; idx += 512){
    const int h = idx / 196, c4 = idx % 196;
    ushort4 u4 = *(const ushort4*)(S_b + base + h*rowstr + c4*4);
    float* d = sv + h*NK_ + c4*4;
    d[0]=b2f(u4.x); d[1]=b2f(u4.y); d[2]=b2f(u4.z); d[3]=b2f(u4.w);
  }
  __syncthreads();

  const int g = wave;
  float wgt[8];
#pragma unroll
  for(int h=0;h<8;h++) wgt[h] = tw[h*8+g];

  float xs[13];
  float lmax = -1e30f;
#pragma unroll
  for(int j=0;j<13;j++){
    const int k = j*64 + lane;
    if(k < NK_){
      float x = 0.f;
#pragma unroll
      for(int h=0;h<8;h++) x += wgt[h]*sv[h*NK_+k];
      xs[j] = x;
      lmax = fmaxf(lmax, x);
    } else xs[j] = -1e30f;
  }
#pragma unroll
  for(int off=32; off>=1; off>>=1) lmax = fmaxf(lmax, __shfl_xor(lmax, off));

  float lsum = 0.f;
#pragma unroll
  for(int j=0;j<13;j++){
    const int k = j*64 + lane;
    if(k < NK_){
      const float e = __expf(xs[j] - lmax);
      xs[j] = e; lsum += e;
    }
  }
#pragma unroll
  for(int off=32; off>=1; off>>=1) lsum += __shfl_xor(lsum, off);
  const float inv = 1.0f/lsum;

  u16* dst = S_b + base + g*rowstr;
  float lss = 0.f;
#pragma unroll
  for(int j=0;j<13;j++){
    const int k = j*64 + lane;
    if(k < NK_){
      const float dev = xs[j]*inv - (1.0f/NK_);
      dst[k] = f2b(dev);
      lss += dev*dev;
    }
  }
  for(int k = NK_ + lane; k < NKP_; k += 64) dst[k] = 0;
#pragma unroll
  for(int off=32; off>=1; off>>=1) lss += __shfl_xor(lss, off);
  if(lane==0) partial_b[g*NQ_ + qi] = lss;
}

// column sums of V, k-split into 8 chunks of 98 -> part[kc][hd]
__global__ __launch_bounds__(256)
void colsum_v(const u16* __restrict__ Vf_b, float* __restrict__ part, int sV){
  const int hd = blockIdx.x*256 + threadIdx.x;
  const int kc = blockIdx.y;
  const u16* p = Vf_b + (long long)kc*98*sV + hd;
  float s=0.f;
  for(int k=0;k<98;k++) s += b2f(p[(long long)k*sV]);
  part[(long long)kc*HD_ + hd] = s;
}

__global__ __launch_bounds__(256)
void finalize_stats(const float* __restrict__ partial_b, const float* __restrict__ bng_b,
                    const float* __restrict__ bnb_b, float* __restrict__ a_b,
                    float* __restrict__ c_b){
  const int g = blockIdx.x;
  const int t = threadIdx.x;
  __shared__ float red[4];
  float s = 0.f;
  for(int i=t; i<NQ_; i+=256) s += partial_b[g*NQ_ + i];
#pragma unroll
  for(int off=32; off>=1; off>>=1) s += __shfl_xor(s, off);
  if((t&63)==0) red[t>>6] = s;
  __syncthreads();
  if(t==0){
    const float tot = red[0]+red[1]+red[2]+red[3];
    const float s2 = tot * (1.0f/((float)NQ_*(float)NK_));
    a_b[g] = bng_b[g]*rsqrtf(s2 + 1e-3f);
    c_b[g] = bnb_b[g];
  }
}

// corr_b[n] = sum_g c_b[g] * (colsumV_b[g*512:(g+1)*512] . Wo_g[:,n]); colsum k-split
__global__ __launch_bounds__(256)
void corr_kernel(const float* __restrict__ part, const u16* __restrict__ Wot,
                 const float* __restrict__ c_b, float* __restrict__ corr_b){
  const int n = blockIdx.x, t = threadIdx.x;
  __shared__ float red[256];
  float s = 0.f;
  for(int hd=t; hd<HD_; hd+=256){
    float cs = 0.f;
#pragma unroll
    for(int kc=0; kc<8; kc++) cs += part[(long long)kc*HD_ + hd];
    s += c_b[hd>>9] * cs * b2f(Wot[(long long)n*HD_+hd]);
  }
  red[t]=s; __syncthreads();
  for(int st=128; st>0; st>>=1){ if(t<st) red[t]+=red[t+st]; __syncthreads(); }
  if(t==0) corr_b[n]=red[0];
}

// ---------------------------------------------------------------------------
extern "C" void kernel_launch(void* const* d_in, const int* in_sizes, int n_in,
                              void* d_out, int out_size, void* d_ws, size_t ws_size,
                              hipStream_t stream)
{
  (void)in_sizes; (void)n_in; (void)out_size;
  const float* queries = (const float*)d_in[0];
  const float* Wq  = (const float*)d_in[3];
  const float* bq  = (const float*)d_in[4];
  const float* Wk  = (const float*)d_in[5];
  const float* bk  = (const float*)d_in[6];
  const float* Wv  = (const float*)d_in[7];
  const float* bv  = (const float*)d_in[8];
  const float* Wo  = (const float*)d_in[9];
  const float* bo  = (const float*)d_in[10];
  const float* srk = (const float*)d_in[11];
  const float* srb = (const float*)d_in[12];
  const float* lng = (const float*)d_in[13];
  const float* lnb = (const float*)d_in[14];
  const float* tw  = (const float*)d_in[15];
  const float* bng = (const float*)d_in[17];
  const float* bnb = (const float*)d_in[18];
  float* out = (float*)d_out;
  const float QSC = 0.04419417382415922f;   // 1/sqrt(512)

  char* w = (char*)d_ws;
  size_t off = 0;
  auto alloc = [&](size_t bytes)->char*{
    char* p = w + off; off += (bytes + 255) & ~(size_t)255; return p;
  };

  const bool tierA = (ws_size >= (size_t)210*1024*1024);

  u16* Wqt = (u16*)alloc((size_t)HD_*C_*2);
  u16* Wkt = (u16*)alloc((size_t)HD_*C_*2);   // Wvt follows contiguously
  u16* Wvt = (u16*)alloc((size_t)HD_*C_*2);
  u16* Wot = (u16*)alloc((size_t)C_*HD_*2);
  u16* x   = (u16*)alloc((size_t)B_*NK_*C_*2 + 262144);     // +256K over-read pad
  float* bkv = (float*)alloc((size_t)2*HD_*4);              // bk || bv
  u16* Qin;
  u16* QfU;
  if(tierA){
    Qin = (u16*)alloc((size_t)B_*NQ_*C_*2);
    QfU = (u16*)alloc((size_t)B_*NQ_*HD_*2 + 2097152);      // +2M: score A over-read
  } else {
    Qin = (u16*)alloc((size_t)NQ_*C_*2 + 262144);
    QfU = (u16*)alloc((size_t)NQ_*HD_*2 + 2097152);
  }
  u16* KV_b = (u16*)alloc((size_t)NK_*2*HD_*2 + 4194304);  // +4M: score B over-read
  u16* Vt_b = (u16*)alloc((size_t)HD_*NKP_*2);
  u16* S_b  = (u16*)alloc((size_t)8*NQ_*NKP_*2 + 524288);   // +512K PV A over-read pad
  float* colsum  = (float*)alloc((size_t)8*HD_*4);          // k-split partials (per batch)
  float* partial = (float*)alloc((size_t)8*NQ_*4);
  float* aArr    = (float*)alloc(256);
  float* cArr    = (float*)alloc(256);
  float* corrB   = (float*)alloc((size_t)B_*C_*4);

  // ---- weight prep + conv+LN ----
  wt_kernel<<<dim3(128,16), 256, 0, stream>>>(Wq, Wqt, 512, 4096);
  wt_kernel<<<dim3(128,16), 256, 0, stream>>>(Wk, Wkt, 512, 4096);
  wt_kernel<<<dim3(128,16), 256, 0, stream>>>(Wv, Wvt, 512, 4096);
  wt_kernel<<<dim3(16,128), 256, 0, stream>>>(Wo, Wot, 4096, 512);
  conv_ln<<<B_*NK_, 256, 0, stream>>>(queries, srk, srb, lng, lnb, x);
  hipMemcpyAsync(bkv,      bk, HD_*4, hipMemcpyDeviceToDevice, stream);
  hipMemcpyAsync(bkv+HD_,  bv, HD_*4, hipMemcpyDeviceToDevice, stream);

  if(tierA){
    cvt_bf16<<<6272, 256, 0, stream>>>(queries, Qin, (long long)B_*NQ_*C_);
    // Qf = (queries@Wq + bq)/sqrt(512); panel order mp=4 x np=2:
    // per XCD: B-half (2MB) L2-resident, A-quarter streamed once.
    gemm128<0><<<dim3(49,32,1),256,0,stream>>>(Qin, Wqt, QfU, B_*NQ_, 4096, 512,
        512, 512, HD_, 1, 0,0,0,0,0,0, bq, QSC, nullptr, nullptr, 1, 0, 4, 2);
  }

  for(int b=0; b<B_; b++){
    u16* Qf_b = tierA ? (QfU + (size_t)b*NQ_*HD_) : QfU;
    if(!tierA){
      cvt_bf16<<<1568, 256, 0, stream>>>(queries + (size_t)b*NQ_*C_, Qin, (long long)NQ_*C_);
      gemm128<0><<<dim3(13,32,1),256,0,stream>>>(Qin, Wqt, Qf_b, NQ_, 4096, 512,
          512, 512, HD_, 1, 0,0,0,0,0,0, bq, QSC, nullptr, nullptr, 1, 0, 4, 2);
    }
    const u16* x_b = x + (size_t)b*NK_*C_;
    // combined K|V projection: B spans Wkt..Wvt (adjacent, 8192 rows)
    gemm128<0><<<dim3(4,64,1),256,0,stream>>>(x_b, Wkt, KV_b, NK_, 2*HD_, 512,
        512, 512, 2*HD_, 1, 0,0,0,0,0,0, bkv, 1.0f, nullptr, nullptr, 1, 0, 0, 0);
    vt_kernel<<<dim3(26,128),256,0,stream>>>(KV_b + HD_, Vt_b, 2*HD_);
    colsum_v<<<dim3(16,8),256,0,stream>>>(KV_b + HD_, colsum, 2*HD_);
    // per-head scores: S_b[z] = Qf_b[:, z*512:+512] @ K_b[:, z*512:+512]^T
    // by-inner order: one z per XCD (91 blocks), A/B slices L2-resident.
    gemm128<0><<<dim3(13,7,8),256,0,stream>>>(Qf_b, KV_b, S_b, NQ_, NKP_, 512,
        HD_, 2*HD_, NKP_, 8, 0, 512, 0, 512, 0, (long long)NQ_*NKP_,
        nullptr, 1.0f, nullptr, nullptr, 1, 0, 0, 0);
    mix_softmax<<<NQ_, 512, 0, stream>>>(S_b, tw, partial);
    finalize_stats<<<8,256,0,stream>>>(partial, bng + b*8, bnb + b*8, aArr + b*8, cArr + b*8);
    corr_kernel<<<512,256,0,stream>>>(colsum, Wot, cArr + b*8, corrB + b*C_);
    // U_b[:, z*512+d] = a[b,z] * (P~_z @ V_z)
    gemm128<0><<<dim3(13,4,8),256,0,stream>>>(S_b, Vt_b, Qf_b, NQ_, 512, NKP_,
        NKP_, NKP_, HD_, 8, 0, (long long)NQ_*NKP_, 0, (long long)512*NKP_, 0, 512,
        nullptr, 1.0f, aArr + b*8, nullptr, 1, 0, 0, 0);
    if(!tierA){
      gemm128<1><<<dim3(13,4,1),256,0,stream>>>(Qf_b, Wot, out + (size_t)b*NQ_*C_,
          NQ_, 512, HD_, HD_, HD_, C_,
          1, 0,0,0,0,0,0, bo, 1.0f, nullptr, corrB + b*C_, NQ_, C_, 0, 0);
    }
  }

  if(tierA){
    // out-proj: by-inner m204 (was identity: U re-read ~4x) -> U read once.
    gemm128<1><<<dim3(49,4,1),256,0,stream>>>(QfU, Wot, out, B_*NQ_, 512, HD_,
        HD_, HD_, C_, 1, 0,0,0,0,0,0, bo, 1.0f, nullptr, corrB, NQ_, C_, 0, 0);
  }
}